// Round 5
// baseline (534.958 us; speedup 1.0000x reference)
//
#include <hip/hip_runtime.h>
#include <math.h>

#define DUR 32
#define DIM 256
#define TT  528   // sum_b (32-b)

// ws layout (floats)
#define WS_C 0        // [528]  c[t] = col-sums of normalized branches
#define WS_S 528      // [528]  s = Wv @ c + 256*bv
#define WS_Y 2048     // [32*256*32] raw conv outputs y[b][o][t]

__device__ __forceinline__ float gelu_exact(float v) {
    return 0.5f * v * (1.0f + erff(v * 0.70710678118654752f));
}

// ---------------- conv: pure streaming W, write raw y ----------------
// Block = (b, 8 o's). K4 = ceil(k/4) compile-time class (covers 4 b's).
// Lmax = 36-4*K4 bounds acc[]; arrays anti-correlated -> no spill at 128 VGPR.
template<int K4>
__device__ __forceinline__ void conv_body(
    const int bb, const int o0, const int tid,
    const float* __restrict__ x, const float* __restrict__ W,
    float* __restrict__ ws, char* __restrict__ smem, float (* __restrict__ red)[4][32])
{
    constexpr int Lmax  = 36 - 4 * K4;
    constexpr int DEPTH = (K4 <= 4) ? 2 : 1;
    constexpr int BUFB  = 256 * 16 * K4;   // bytes per LDS buffer
    const int k = bb + 1;                  // uniform
    const int L = 32 - bb;                 // uniform, <= Lmax
    const int wave = tid >> 6, lane = tid & 63;

    // x column for channel n=tid (coalesced); pad taps (weights zero there)
    float xv[35];
#pragma unroll
    for (int tau = 0; tau < 32; ++tau) xv[tau] = x[tau * DIM + tid];
    xv[32] = 0.f; xv[33] = 0.f; xv[34] = 0.f;

    const float* Wb = W + (size_t)bb * (DIM * DIM * DUR) + (size_t)o0 * (DIM * DUR);

    float4 wregA[K4];
    float4 wregB[DEPTH == 2 ? K4 : 1];

    auto issue = [&](int oo, float4* dst) {
#pragma unroll
        for (int r = 0; r < K4; ++r) {
            const int e = r * 256 + tid;
            const int n = e / K4, m = e - n * K4;        // magic-div, K4 constexpr
            dst[r] = *(const float4*)(Wb + (size_t)oo * (DIM * DUR) + n * 32 + m * 4);
        }
    };
    auto stage = [&](int p, const float4* src) {
#pragma unroll
        for (int r = 0; r < K4; ++r) {
            const int e = r * 256 + tid;
            const int n = e / K4, m = e - n * K4;
            *(float4*)(smem + p * BUFB + (n * K4 + (m + n) % K4) * 16) = src[r];
        }
    };
    auto compute = [&](int p) {
        float acc[Lmax];
#pragma unroll
        for (int t = 0; t < Lmax; ++t) acc[t] = 0.f;
        const char* myrow = smem + p * BUFB + tid * (16 * K4);
#pragma unroll
        for (int m = 0; m < K4; ++m) {
            float4 w4 = *(const float4*)(myrow + ((m + tid) % K4) * 16);
            if (4 * m + 0 >= k) w4.x = 0.f;   // uniform k; only last quad trims
            if (4 * m + 1 >= k) w4.y = 0.f;
            if (4 * m + 2 >= k) w4.z = 0.f;
            if (4 * m + 3 >= k) w4.w = 0.f;
#pragma unroll
            for (int t = 0; t < Lmax; ++t) {
                if (t < L) {   // uniform
                    acc[t] = fmaf(xv[t + 4*m + 0], w4.x, acc[t]);
                    acc[t] = fmaf(xv[t + 4*m + 1], w4.y, acc[t]);
                    acc[t] = fmaf(xv[t + 4*m + 2], w4.z, acc[t]);
                    acc[t] = fmaf(xv[t + 4*m + 3], w4.w, acc[t]);
                }
            }
        }
#pragma unroll
        for (int t = 0; t < Lmax; ++t) {
            if (t < L) {   // uniform
                float v = acc[t];
                v += __shfl_down(v, 32, 64);
                v += __shfl_down(v, 16, 64);
                v += __shfl_down(v, 8, 64);
                v += __shfl_down(v, 4, 64);
                v += __shfl_down(v, 2, 64);
                v += __shfl_down(v, 1, 64);
                if (lane == 0) red[p][wave][t] = v;
            }
        }
    };
    auto epilogue = [&](int j) {       // one wave: combine partials, store raw y
        const int o = o0 + j;
        if (lane < L) {
            const int q = j & 1;
            const float y = red[q][0][lane] + red[q][1][lane]
                          + red[q][2][lane] + red[q][3][lane];
            ws[WS_Y + bb * 8192 + o * 32 + lane] = y;
        }
    };

    if constexpr (DEPTH == 2) {
        issue(0, wregA);
        issue(1, wregB);
#pragma unroll
        for (int s = 0; s < 4; ++s) {
            const int ooA = 2 * s, ooB = 2 * s + 1;
            stage(0, wregA);
            __syncthreads();
            if (ooA + 2 < 8) issue(ooA + 2, wregA);
            if (ooA > 0 && wave == ((ooA - 1) & 3)) epilogue(ooA - 1);
            compute(0);
            stage(1, wregB);
            __syncthreads();
            if (ooB + 2 < 8) issue(ooB + 2, wregB);
            if (wave == ((ooB - 1) & 3)) epilogue(ooB - 1);
            compute(1);
        }
    } else {
        issue(0, wregA);
#pragma unroll
        for (int oo = 0; oo < 8; ++oo) {
            stage(oo & 1, wregA);
            __syncthreads();
            if (oo + 1 < 8) issue(oo + 1, wregA);
            if (oo > 0 && wave == ((oo - 1) & 3)) epilogue(oo - 1);
            compute(oo & 1);
        }
    }
    __syncthreads();
    if (wave == 3) epilogue(7);   // 7 & 3 == 3
}

__global__ __launch_bounds__(256, 4) void conv_kernel(
    const float* __restrict__ x, const float* __restrict__ W, float* __restrict__ ws)
{
    __shared__ char  smem[65536];        // 2 buffers, max K4=8
    __shared__ float red[2][4][32];

    const int bid = blockIdx.x;
    const int bb  = 31 - (bid & 31);     // interleave classes across CUs
    const int o0  = (bid >> 5) * 8;
    const int tid = threadIdx.x;

    switch (bb >> 2) {
        case 0: conv_body<1>(bb, o0, tid, x, W, ws, smem, red); break;
        case 1: conv_body<2>(bb, o0, tid, x, W, ws, smem, red); break;
        case 2: conv_body<3>(bb, o0, tid, x, W, ws, smem, red); break;
        case 3: conv_body<4>(bb, o0, tid, x, W, ws, smem, red); break;
        case 4: conv_body<5>(bb, o0, tid, x, W, ws, smem, red); break;
        case 5: conv_body<6>(bb, o0, tid, x, W, ws, smem, red); break;
        case 6: conv_body<7>(bb, o0, tid, x, W, ws, smem, red); break;
        default: conv_body<8>(bb, o0, tid, x, W, ws, smem, red); break;
    }
}

// ---------------- branch epilogue: bias+gelu+LN stats -> c[t] ----------------
// One block per b; wave w handles o in [64w, 64w+64); lane = t.
__global__ __launch_bounds__(256) void branch_kernel(
    const float* __restrict__ convb, const float* __restrict__ lnw,
    const float* __restrict__ lnb, float* __restrict__ ws)
{
    const int b = blockIdx.x;
    const int L = 32 - b;
    const int tid = threadIdx.x;
    const int wave = tid >> 6, lane = tid & 63;

    float a1 = 0.f, a2 = 0.f, a3 = 0.f, s1 = 0.f, s2 = 0.f;
    for (int oi = 0; oi < 64; ++oi) {
        const int o = wave * 64 + oi;
        float g = 0.f;
        if (lane < L) {
            const float y = ws[WS_Y + b * 8192 + o * 32 + lane] + convb[b * DIM + o];
            g = gelu_exact(y);
            const float lw = lnw[(size_t)(b * DIM + o) * DUR + lane];
            const float lb = lnb[(size_t)(b * DIM + o) * DUR + lane];
            a1 += g * lw; a2 += lw; a3 += lb;
        }
        s1 += g; s2 += g * g;
    }
    __shared__ float ra[4][32], rb2[4][32], rc[4][32], rs[4][2];
    {
        float u = s1, v = s2;
        u += __shfl_xor(u, 32, 64); v += __shfl_xor(v, 32, 64);
        u += __shfl_xor(u, 16, 64); v += __shfl_xor(v, 16, 64);
        u += __shfl_xor(u, 8, 64);  v += __shfl_xor(v, 8, 64);
        u += __shfl_xor(u, 4, 64);  v += __shfl_xor(v, 4, 64);
        u += __shfl_xor(u, 2, 64);  v += __shfl_xor(v, 2, 64);
        u += __shfl_xor(u, 1, 64);  v += __shfl_xor(v, 1, 64);
        if (lane == 0) { rs[wave][0] = u; rs[wave][1] = v; }
    }
    if (lane < 32) { ra[wave][lane] = a1; rb2[wave][lane] = a2; rc[wave][lane] = a3; }
    __syncthreads();
    if (wave == 0 && lane < L) {
        const float A1 = ra[0][lane] + ra[1][lane] + ra[2][lane] + ra[3][lane];
        const float A2 = rb2[0][lane] + rb2[1][lane] + rb2[2][lane] + rb2[3][lane];
        const float A3 = rc[0][lane] + rc[1][lane] + rc[2][lane] + rc[3][lane];
        const float S1 = rs[0][0] + rs[1][0] + rs[2][0] + rs[3][0];
        const float S2 = rs[0][1] + rs[1][1] + rs[2][1] + rs[3][1];
        const float cnt = 256.f * (float)L;
        const float mu = S1 / cnt;
        const float r  = rsqrtf(S2 / cnt - mu * mu + 1e-5f);
        const int boff = b * 32 - (b * (b - 1)) / 2;
        ws[WS_C + boff + lane] = r * (A1 - mu * A2) + A3;
    }
}

// ---------------- proj1: s = Wv @ c + 256*bv (132 blocks x 4 rows) ----------------
__global__ __launch_bounds__(256) void proj1_kernel(
    float* __restrict__ ws, const float* __restrict__ in_proj_w,
    const float* __restrict__ in_proj_b)
{
    __shared__ float cc[TT];
    const int n = threadIdx.x;
    for (int t = n; t < TT; t += 256) cc[t] = ws[WS_C + t];
    __syncthreads();
    const int wave = n >> 6, lane = n & 63;
    const int row = blockIdx.x * 4 + wave;
    const float* Wr = in_proj_w + (size_t)(2 * TT + row) * TT;
    float a = 0.f;
    for (int t = lane; t < TT; t += 64) a = fmaf(Wr[t], cc[t], a);
    a += __shfl_down(a, 32, 64);
    a += __shfl_down(a, 16, 64);
    a += __shfl_down(a, 8, 64);
    a += __shfl_down(a, 4, 64);
    a += __shfl_down(a, 2, 64);
    a += __shfl_down(a, 1, 64);
    if (lane == 0) ws[WS_S + row] = a + 256.f * in_proj_b[2 * TT + row];
}

// ---------------- proj2: S rows + pooled mean (4 blocks) ----------------
__global__ __launch_bounds__(256) void proj2_kernel(
    const float* __restrict__ ws, const float* __restrict__ out_proj_w,
    const float* __restrict__ out_proj_b, float* __restrict__ out)
{
    __shared__ float sv[TT];
    __shared__ float Sacc[32];
    __shared__ float mv;
    const int n = threadIdx.x;
    for (int t = n; t < TT; t += 256) sv[t] = ws[WS_S + t];
    __syncthreads();
    const int wave = n >> 6, lane = n & 63;
#pragma unroll
    for (int jj = 0; jj < 8; ++jj) {
        const int j = wave * 8 + jj;
        const int u = blockIdx.x * 128 + j;
        const float* Or = out_proj_w + (size_t)u * TT;
        float a = 0.f;
        for (int t = lane; t < TT; t += 64) a = fmaf(Or[t], sv[t], a);
        a += __shfl_down(a, 32, 64);
        a += __shfl_down(a, 16, 64);
        a += __shfl_down(a, 8, 64);
        a += __shfl_down(a, 4, 64);
        a += __shfl_down(a, 2, 64);
        a += __shfl_down(a, 1, 64);
        if (lane == 0) Sacc[j] = a + 256.f * out_proj_b[u];
    }
    __syncthreads();
    if (n == 0) {
        float m = 0.f;
#pragma unroll
        for (int j = 0; j < 32; ++j) m += Sacc[j];
        mv = m * (1.0f / 32.0f);
    }
    __syncthreads();
    out[blockIdx.x * 256 + n] = mv;
}

extern "C" void kernel_launch(void* const* d_in, const int* in_sizes, int n_in,
                              void* d_out, int out_size, void* d_ws, size_t ws_size,
                              hipStream_t stream)
{
    const float* x   = (const float*)d_in[0];
    const float* W   = (const float*)d_in[1];
    const float* cb  = (const float*)d_in[2];
    const float* lnw = (const float*)d_in[3];
    const float* lnb = (const float*)d_in[4];
    const float* ipw = (const float*)d_in[5];
    const float* ipb = (const float*)d_in[6];
    const float* opw = (const float*)d_in[7];
    const float* opb = (const float*)d_in[8];
    float* ws  = (float*)d_ws;
    float* out = (float*)d_out;

    conv_kernel<<<1024, 256, 0, stream>>>(x, W, ws);
    branch_kernel<<<32, 256, 0, stream>>>(cb, lnw, lnb, ws);
    proj1_kernel<<<132, 256, 0, stream>>>(ws, ipw, ipb);
    proj2_kernel<<<4, 256, 0, stream>>>(ws, opw, opb, out);
}

// Round 6
// 450.332 us; speedup vs baseline: 1.1879x; 1.1879x over previous
//
#include <hip/hip_runtime.h>
#include <math.h>
#include <stdint.h>

#define DUR 32
#define DIM 256
#define TT  528   // sum_b (32-b)

// ws layout (floats)
#define WS_BSUM 0       // [32]
#define WS_BSQ  32      // [32]
#define WS_CY   64      // [528]
#define WS_CW   592     // [528]
#define WS_CB   1120    // [528]
#define WS_S    1648    // [528]
#define WS_S2   2176    // [128]
#define WS_ZERO_FLOATS 1648

__device__ __forceinline__ float gelu_exact(float v) {
    return 0.5f * v * (1.0f + erff(v * 0.70710678118654752f));
}

// async global->LDS, 16 B per lane; dest = (uniform) lds base + lane*16
__device__ __forceinline__ void gl_lds16(const float* g, float* l) {
    __builtin_amdgcn_global_load_lds(
        (const __attribute__((address_space(1))) uint32_t*)g,
        (__attribute__((address_space(3))) uint32_t*)l, 16, 0, 0);
}

// Block = (b, 8 o's). Weights DMA'd to LDS (source-permuted for the rotation
// swizzle), thread n reads back its row. No register staging -> no spills.
template<int K4>
__device__ __forceinline__ void conv_body(
    const int bb, const int o0, const int tid,
    const float* __restrict__ x, const float* __restrict__ W,
    const float* __restrict__ convb, const float* __restrict__ lnw,
    const float* __restrict__ lnb, float* __restrict__ ws,
    float* __restrict__ smem, float (* __restrict__ red)[4][32],
    float (* __restrict__ epi)[4][32], float (* __restrict__ sred)[2])
{
    constexpr int Lmax = 36 - 4 * K4;     // max L in this class
    constexpr int BUFF = 256 * K4 * 4;    // floats per LDS buffer
    const int k = bb + 1;                 // uniform
    const int L = 32 - bb;                // uniform, <= Lmax
    const int wave = tid >> 6, lane = tid & 63;

    // x column for channel n=tid (coalesced); pad taps hit zero weights
    float xv[35];
#pragma unroll
    for (int tau = 0; tau < 32; ++tau) xv[tau] = x[tau * DIM + tid];
    xv[32] = 0.f; xv[33] = 0.f; xv[34] = 0.f;

    const float* Wb = W + (size_t)bb * (DIM * DIM * DUR) + (size_t)o0 * (DIM * DUR);

    // source float-offset for each r-chunk: slot s = r*256+tid holds
    // (row n = s/K4, pos j = s%K4) = logical quad m = (j - n) mod K4
    int srcoff[K4];
#pragma unroll
    for (int r = 0; r < K4; ++r) {
        const int s = r * 256 + tid;
        const int n = s / K4;                  // constexpr K4 -> magic mul
        const int j = s - n * K4;
        int m = j - (n % K4); if (m < 0) m += K4;
        srcoff[r] = n * 32 + m * 4;
    }

    auto issue = [&](int oo, int p) {
        float* base = smem + p * BUFF;
#pragma unroll
        for (int r = 0; r < K4; ++r) {
            float* l = base + (r * 256 + wave * 64) * 4;   // wave-uniform base
            const float* g = Wb + (size_t)oo * 8192 + srcoff[r];
            gl_lds16(g, l);
        }
    };

    auto compute = [&](int p) {
        float acc[Lmax];
#pragma unroll
        for (int t = 0; t < Lmax; ++t) acc[t] = 0.f;
        const float* myrow = smem + p * BUFF + tid * (K4 * 4);
#pragma unroll
        for (int m = 0; m < K4; ++m) {
            const int slot = (m + tid) % K4;               // rotation swizzle
            float4 w4 = *(const float4*)(myrow + slot * 4);
            if (4 * m + 0 >= k) w4.x = 0.f;    // uniform k, literal index
            if (4 * m + 1 >= k) w4.y = 0.f;
            if (4 * m + 2 >= k) w4.z = 0.f;
            if (4 * m + 3 >= k) w4.w = 0.f;
#pragma unroll
            for (int t = 0; t < Lmax; ++t) {
                if (t < L) {   // uniform
                    acc[t] = fmaf(xv[t + 4*m + 0], w4.x, acc[t]);
                    acc[t] = fmaf(xv[t + 4*m + 1], w4.y, acc[t]);
                    acc[t] = fmaf(xv[t + 4*m + 2], w4.z, acc[t]);
                    acc[t] = fmaf(xv[t + 4*m + 3], w4.w, acc[t]);
                }
            }
        }
#pragma unroll
        for (int t = 0; t < Lmax; ++t) {
            if (t < L) {   // uniform
                float v = acc[t];
                v += __shfl_down(v, 32, 64);
                v += __shfl_down(v, 16, 64);
                v += __shfl_down(v, 8, 64);
                v += __shfl_down(v, 4, 64);
                v += __shfl_down(v, 2, 64);
                v += __shfl_down(v, 1, 64);
                if (lane == 0) red[p][wave][t] = v;
            }
        }
    };

    float cy = 0.f, cw = 0.f, cbv = 0.f, s1 = 0.f, s2 = 0.f;

    auto epilogue = [&](int j) {     // one wave: finalize o = o0+j into stats regs
        const int o = o0 + j;
        float g = 0.f;
        if (lane < L) {
            const int q = j & 1;
            const float y = red[q][0][lane] + red[q][1][lane]
                          + red[q][2][lane] + red[q][3][lane]
                          + convb[bb * DIM + o];
            g = gelu_exact(y);
            const float lw = lnw[((size_t)(bb * DIM + o)) * DUR + lane];
            const float lb = lnb[((size_t)(bb * DIM + o)) * DUR + lane];
            cy += g * lw; cw += lw; cbv += lb;
        }
        s1 += g; s2 += g * g;
    };

    issue(0, 0);
#pragma unroll
    for (int oo = 0; oo < 8; ++oo) {
        __syncthreads();                         // drains DMA(oo); red[] ordering
        if (oo < 7) issue(oo + 1, (oo + 1) & 1); // DMA overlaps epilogue+compute
        if (oo > 0 && wave == ((oo - 1) & 3)) epilogue(oo - 1);
        compute(oo & 1);
    }
    __syncthreads();
    if (wave == 3) epilogue(7);   // 7 & 3 == 3

    // cross-wave combine + one atomic set per block
    if (lane < 32) {
        epi[0][wave][lane] = cy;
        epi[1][wave][lane] = cw;
        epi[2][wave][lane] = cbv;
    }
    {
        float a = s1, b2 = s2;
        a += __shfl_down(a, 32, 64);  b2 += __shfl_down(b2, 32, 64);
        a += __shfl_down(a, 16, 64);  b2 += __shfl_down(b2, 16, 64);
        a += __shfl_down(a, 8, 64);   b2 += __shfl_down(b2, 8, 64);
        a += __shfl_down(a, 4, 64);   b2 += __shfl_down(b2, 4, 64);
        a += __shfl_down(a, 2, 64);   b2 += __shfl_down(b2, 2, 64);
        a += __shfl_down(a, 1, 64);   b2 += __shfl_down(b2, 1, 64);
        if (lane == 0) { sred[wave][0] = a; sred[wave][1] = b2; }
    }
    __syncthreads();
    if (wave == 0 && lane < L) {
        const int tg = bb * 32 - (bb * (bb - 1)) / 2 + lane;
        atomicAdd(ws + WS_CY + tg, epi[0][0][lane] + epi[0][1][lane] + epi[0][2][lane] + epi[0][3][lane]);
        atomicAdd(ws + WS_CW + tg, epi[1][0][lane] + epi[1][1][lane] + epi[1][2][lane] + epi[1][3][lane]);
        atomicAdd(ws + WS_CB + tg, epi[2][0][lane] + epi[2][1][lane] + epi[2][2][lane] + epi[2][3][lane]);
    }
    if (tid == 0) {
        atomicAdd(ws + WS_BSUM + bb, sred[0][0] + sred[1][0] + sred[2][0] + sred[3][0]);
        atomicAdd(ws + WS_BSQ  + bb, sred[0][1] + sred[1][1] + sred[2][1] + sred[3][1]);
    }
}

__global__ __launch_bounds__(256, 2) void conv_kernel(
    const float* __restrict__ x, const float* __restrict__ W,
    const float* __restrict__ convb, const float* __restrict__ lnw,
    const float* __restrict__ lnb, float* ws)
{
    __shared__ float smem[2 * 256 * 8 * 4];   // 64 KB: 2 buffers, max K4=8
    __shared__ float red[2][4][32];
    __shared__ float epi[3][4][32];
    __shared__ float sred[4][2];

    const int bid = blockIdx.x;
    const int bb  = 31 - (bid & 31);     // interleave classes across CUs
    const int o0  = (bid >> 5) * 8;
    const int tid = threadIdx.x;

    switch (bb >> 2) {
        case 0: conv_body<1>(bb, o0, tid, x, W, convb, lnw, lnb, ws, smem, red, epi, sred); break;
        case 1: conv_body<2>(bb, o0, tid, x, W, convb, lnw, lnb, ws, smem, red, epi, sred); break;
        case 2: conv_body<3>(bb, o0, tid, x, W, convb, lnw, lnb, ws, smem, red, epi, sred); break;
        case 3: conv_body<4>(bb, o0, tid, x, W, convb, lnw, lnb, ws, smem, red, epi, sred); break;
        case 4: conv_body<5>(bb, o0, tid, x, W, convb, lnw, lnb, ws, smem, red, epi, sred); break;
        case 5: conv_body<6>(bb, o0, tid, x, W, convb, lnw, lnb, ws, smem, red, epi, sred); break;
        case 6: conv_body<7>(bb, o0, tid, x, W, convb, lnw, lnb, ws, smem, red, epi, sred); break;
        default: conv_body<8>(bb, o0, tid, x, W, convb, lnw, lnb, ws, smem, red, epi, sred); break;
    }
}

// c[t] from LN stats + colsums, then s = Wv @ c + 256*bv. 132 blocks x 4 rows.
__global__ __launch_bounds__(256) void proj1_kernel(
    float* ws, const float* __restrict__ in_proj_w,
    const float* __restrict__ in_proj_b)
{
    __shared__ float cc[TT];
    __shared__ float mu_s[32], r_s[32];
    __shared__ int map[TT];
    const int n = threadIdx.x;
    if (n < 32) {
        const int Lb = 32 - n;
        const float cnt = 256.f * (float)Lb;
        const float mu = ws[WS_BSUM + n] / cnt;
        const float var = ws[WS_BSQ + n] / cnt - mu * mu;
        mu_s[n] = mu;
        r_s[n] = rsqrtf(var + 1e-5f);
        const int off = n * 32 - (n * (n - 1)) / 2;
        for (int t = 0; t < Lb; ++t) map[off + t] = n;
    }
    __syncthreads();
    for (int t = n; t < TT; t += 256) {
        const int b = map[t];
        cc[t] = (ws[WS_CY + t] - mu_s[b] * ws[WS_CW + t]) * r_s[b] + ws[WS_CB + t];
    }
    __syncthreads();
    const int wave = n >> 6, lane = n & 63;
    const int row = blockIdx.x * 4 + wave;
    const float* Wr = in_proj_w + (size_t)(2 * TT + row) * TT;
    float a = 0.f;
    for (int t = lane; t < TT; t += 64) a = fmaf(Wr[t], cc[t], a);
    a += __shfl_down(a, 32, 64);
    a += __shfl_down(a, 16, 64);
    a += __shfl_down(a, 8, 64);
    a += __shfl_down(a, 4, 64);
    a += __shfl_down(a, 2, 64);
    a += __shfl_down(a, 1, 64);
    if (lane == 0) ws[WS_S + row] = a + 256.f * in_proj_b[2 * TT + row];
}

// S2[i] = out_proj_w[u,:] . s + 256*opb[u], u = (i>>5)*128 + (i&31). 128 blocks.
__global__ __launch_bounds__(256) void proj2a_kernel(
    float* ws, const float* __restrict__ out_proj_w,
    const float* __restrict__ out_proj_b)
{
    const int i = blockIdx.x;
    const int u = (i >> 5) * 128 + (i & 31);
    const int n = threadIdx.x;
    const int wave = n >> 6, lane = n & 63;
    const float* Or = out_proj_w + (size_t)u * TT;
    float a = 0.f;
    for (int t = n; t < TT; t += 256) a = fmaf(Or[t], ws[WS_S + t], a);
    a += __shfl_down(a, 32, 64);
    a += __shfl_down(a, 16, 64);
    a += __shfl_down(a, 8, 64);
    a += __shfl_down(a, 4, 64);
    a += __shfl_down(a, 2, 64);
    a += __shfl_down(a, 1, 64);
    __shared__ float r4[4];
    if (lane == 0) r4[wave] = a;
    __syncthreads();
    if (n == 0) ws[WS_S2 + i] = r4[0] + r4[1] + r4[2] + r4[3] + 256.f * out_proj_b[u];
}

// out[w*256 + d] = mean_j S2[w*32 + j]. 4 blocks.
__global__ __launch_bounds__(256) void proj2b_kernel(
    const float* __restrict__ ws, float* __restrict__ out)
{
    const int n = threadIdx.x;
    __shared__ float mv;
    if (n < 64) {
        float v = (n < 32) ? ws[WS_S2 + blockIdx.x * 32 + n] : 0.f;
        v += __shfl_down(v, 16, 64);
        v += __shfl_down(v, 8, 64);
        v += __shfl_down(v, 4, 64);
        v += __shfl_down(v, 2, 64);
        v += __shfl_down(v, 1, 64);
        if (n == 0) mv = v * (1.0f / 32.0f);
    }
    __syncthreads();
    out[blockIdx.x * 256 + n] = mv;
}

extern "C" void kernel_launch(void* const* d_in, const int* in_sizes, int n_in,
                              void* d_out, int out_size, void* d_ws, size_t ws_size,
                              hipStream_t stream)
{
    const float* x   = (const float*)d_in[0];
    const float* W   = (const float*)d_in[1];
    const float* cb  = (const float*)d_in[2];
    const float* lnw = (const float*)d_in[3];
    const float* lnb = (const float*)d_in[4];
    const float* ipw = (const float*)d_in[5];
    const float* ipb = (const float*)d_in[6];
    const float* opw = (const float*)d_in[7];
    const float* opb = (const float*)d_in[8];
    float* ws  = (float*)d_ws;
    float* out = (float*)d_out;

    hipMemsetAsync(ws, 0, WS_ZERO_FLOATS * sizeof(float), stream);
    conv_kernel<<<1024, 256, 0, stream>>>(x, W, cb, lnw, lnb, ws);
    proj1_kernel<<<132, 256, 0, stream>>>(ws, ipw, ipb);
    proj2a_kernel<<<128, 256, 0, stream>>>(ws, opw, opb);
    proj2b_kernel<<<4, 256, 0, stream>>>(ws, out);
}